// Round 1
// baseline (5097.959 us; speedup 1.0000x reference)
//
#include <hip/hip_runtime.h>

#define Bq     1024
#define Tq     2048
#define INq    4
#define UNITSq 256
#define BBq    128
#define NCq    10

typedef __bf16 bf16x8 __attribute__((ext_vector_type(8)));
typedef float  f32x4  __attribute__((ext_vector_type(4)));

__device__ __forceinline__ float fast_tanh(float x) {
    // tanh(x) = 1 - 2/(e^{2x}+1); exact at +-inf, no NaN for finite x
    float e = __expf(2.0f * x);
    return 1.0f - 2.0f / (e + 1.0f);
}
__device__ __forceinline__ float fast_sigmoid(float x) {
    return 1.0f / (1.0f + __expf(-x));
}

// 256 blocks x 512 threads. Block b owns batch rows [4b, 4b+4) for all T steps.
// 8 waves/block; wave w owns head-units [32w,32w+32) and backbone cols [16w,16w+16).
__global__ __launch_bounds__(512) void cfc_kernel(
    const float* __restrict__ x,
    const float* __restrict__ W_bb, const float* __restrict__ b_bb,
    const float* __restrict__ W_ff1, const float* __restrict__ b_ff1,
    const float* __restrict__ W_ff2, const float* __restrict__ b_ff2,
    const float* __restrict__ W_ta, const float* __restrict__ b_ta,
    const float* __restrict__ W_tb, const float* __restrict__ b_tb,
    const float* __restrict__ W_fc, const float* __restrict__ b_fc,
    float* __restrict__ out)
{
    const int tid = threadIdx.x;
    const int w   = tid >> 6;    // wave 0..7
    const int l   = tid & 63;
    const int l4  = l >> 4;      // k-group 0..3
    const int lc  = l & 15;      // col-in-tile / A-row
    const int bbase = blockIdx.x * 4;

    // LDS: h (bf16, double buffered, XOR-swizzled rows), bb (bf16, swizzled),
    // x chunk stage (32 steps x 4 rows x 4, double buffered), final h-sum.
    __shared__ __bf16 hb[2][16 * 256];
    __shared__ __bf16 bbuf[16 * 128];
    __shared__ float  xstage[2][4 * 128];
    __shared__ float  hsum_lds[4][256];

    // ---------------- one-time weight preload into MFMA B-fragments ----------
    // B-frag layout (16x16x32): b[j] = B[kt*32 + l4*8 + j][col = lc-of-tile]
    const int ub = w * 32;
    bf16x8 WH[3][2][4];   // [ff1, ff2, ta+tb][unit tile][ktile]
    #pragma unroll
    for (int tl = 0; tl < 2; ++tl) {
        const int u = ub + tl * 16 + lc;
        #pragma unroll
        for (int kt = 0; kt < 4; ++kt) {
            bf16x8 f1, f2, ts;
            #pragma unroll
            for (int j = 0; j < 8; ++j) {
                const int k = kt * 32 + l4 * 8 + j;
                f1[j] = (__bf16)W_ff1[k * UNITSq + u];
                f2[j] = (__bf16)W_ff2[k * UNITSq + u];
                ts[j] = (__bf16)(W_ta[k * UNITSq + u] + W_tb[k * UNITSq + u]);
            }
            WH[0][tl][kt] = f1; WH[1][tl][kt] = f2; WH[2][tl][kt] = ts;
        }
    }
    // Backbone: K = 256 (h, W_bb rows 4..259) + ktile 8 holding x (rows 0..3).
    const int cb = w * 16 + lc;
    bf16x8 WB[9];
    #pragma unroll
    for (int kt = 0; kt < 8; ++kt) {
        bf16x8 f;
        #pragma unroll
        for (int j = 0; j < 8; ++j) {
            const int k = kt * 32 + l4 * 8 + j;      // h index 0..255
            f[j] = (__bf16)W_bb[(4 + k) * BBq + cb];
        }
        WB[kt] = f;
    }
    {
        bf16x8 f;
        #pragma unroll
        for (int j = 0; j < 8; ++j) {
            const int k = l4 * 8 + j;                // 0..31 inside ktile 8
            f[j] = (k < 4) ? (__bf16)W_bb[k * BBq + cb] : (__bf16)0.0f;
        }
        WB[8] = f;
    }
    const float bias_bb = b_bb[cb];
    float bias_h[3][2];
    #pragma unroll
    for (int tl = 0; tl < 2; ++tl) {
        const int u = ub + tl * 16 + lc;
        bias_h[0][tl] = b_ff1[u];
        bias_h[1][tl] = b_ff2[u];
        bias_h[2][tl] = b_ta[u] + b_tb[u];
    }

    // ---------------- init: h0 = 0, x chunk 0 staged, chunk 1 in flight ------
    for (int i = tid; i < 2 * 16 * 256; i += 512) ((__bf16*)hb)[i] = (__bf16)0.0f;
    {
        const int r = tid >> 7, off = tid & 127;
        const int tel = off >> 2, q = off & 3;
        xstage[0][r * 128 + off] = x[((size_t)(bbase + r) * Tq + tel) * INq + q];
    }
    float xv;   // holds chunk (t>>5)+1, one float per thread
    {
        const int r = tid >> 7, off = tid & 127;
        const int tel = 32 + (off >> 2), q = off & 3;
        xv = x[((size_t)(bbase + r) * Tq + tel) * INq + q];
    }
    __syncthreads();

    float hsum[2][4] = {{0.f,0.f,0.f,0.f},{0.f,0.f,0.f,0.f}};
    int cur = 0;

    for (int t = 0; t < Tq; ++t) {
        const int nxt = cur ^ 1;
        const int sb  = (t >> 5) & 1;

        // issue global load of x chunk (t>>5)+2 (consumed 32 steps later)
        float xnew = 0.f;
        if ((t & 31) == 0) {
            const int r = tid >> 7, off = tid & 127;
            int tel = t + 64 + (off >> 2);
            tel = (tel < Tq) ? tel : (Tq - 1);
            const int q = off & 3;
            xnew = x[((size_t)(bbase + r) * Tq + tel) * INq + q];
        }

        // ---- P0: backbone  pre = [x_t | h] @ W_bb + b_bb  -------------------
        f32x4 accB0 = {bias_bb, bias_bb, bias_bb, bias_bb};
        f32x4 accB1 = {0.f, 0.f, 0.f, 0.f};
        #pragma unroll
        for (int kt = 0; kt < 8; ++kt) {
            const int idx = (lc * 256 + kt * 32 + l4 * 8) ^ ((lc & 7) << 3);
            bf16x8 a = *(const bf16x8*)&hb[cur][idx];
            if (kt & 1) accB1 = __builtin_amdgcn_mfma_f32_16x16x32_bf16(a, WB[kt], accB1, 0, 0, 0);
            else        accB0 = __builtin_amdgcn_mfma_f32_16x16x32_bf16(a, WB[kt], accB0, 0, 0, 0);
        }
        {   // ktile 8: x part (A nonzero only lanes l4==0, rows 0..3)
            bf16x8 a;
            #pragma unroll
            for (int j = 0; j < 8; ++j) a[j] = (__bf16)0.0f;
            if (l4 == 0 && lc < 4) {
                const float* xp = &xstage[sb][lc * 128 + (t & 31) * 4];
                a[0] = (__bf16)xp[0]; a[1] = (__bf16)xp[1];
                a[2] = (__bf16)xp[2]; a[3] = (__bf16)xp[3];
            }
            accB1 = __builtin_amdgcn_mfma_f32_16x16x32_bf16(a, WB[8], accB1, 0, 0, 0);
        }
        {   // lecun_tanh + write bb tile (swizzled)
            #pragma unroll
            for (int i = 0; i < 4; ++i) {
                const int row = l4 * 4 + i;
                float pre = accB0[i] + accB1[i];
                float v = 1.7159f * fast_tanh(0.666f * pre);
                bbuf[((row * 128) + cb) ^ ((row & 7) << 3)] = (__bf16)v;
            }
        }
        __syncthreads();   // bar A

        // ---- P1: heads  ff1/ff2/(ta+tb) = bb @ WH + bias --------------------
        f32x4 acc[3][2];
        #pragma unroll
        for (int hh = 0; hh < 3; ++hh)
            #pragma unroll
            for (int tl = 0; tl < 2; ++tl) {
                const float bv = bias_h[hh][tl];
                acc[hh][tl] = (f32x4){bv, bv, bv, bv};
            }
        #pragma unroll
        for (int kt = 0; kt < 4; ++kt) {
            const int idx = (lc * 128 + kt * 32 + l4 * 8) ^ ((lc & 7) << 3);
            bf16x8 a = *(const bf16x8*)&bbuf[idx];
            #pragma unroll
            for (int hh = 0; hh < 3; ++hh)
                #pragma unroll
                for (int tl = 0; tl < 2; ++tl)
                    acc[hh][tl] = __builtin_amdgcn_mfma_f32_16x16x32_bf16(a, WH[hh][tl][kt], acc[hh][tl], 0, 0, 0);
        }
        // h_new = f1 + sigma(ts)*(f2 - f1); accumulate h_sum; write h (swizzled)
        #pragma unroll
        for (int tl = 0; tl < 2; ++tl) {
            #pragma unroll
            for (int i = 0; i < 4; ++i) {
                float f1 = fast_tanh(acc[0][tl][i]);
                float f2 = fast_tanh(acc[1][tl][i]);
                float tt = fast_sigmoid(acc[2][tl][i]);
                float hn = f1 + tt * (f2 - f1);
                hsum[tl][i] += hn;
                const int row = l4 * 4 + i;
                hb[nxt][((row * 256) + (ub + tl * 16 + lc)) ^ ((row & 7) << 3)] = (__bf16)hn;
            }
        }
        // stage x chunk (t>>5)+1 into LDS; rotate in-flight value
        if ((t & 31) == 0) {
            const int r = tid >> 7, off = tid & 127;
            xstage[((t >> 5) + 1) & 1][r * 128 + off] = xv;
            xv = xnew;
        }
        __syncthreads();   // bar B
        cur = nxt;
    }

    // ---------------- epilogue: out = (h_sum/T) @ W_fc + b_fc ----------------
    if (l4 == 0) {   // lanes 0..15 hold real batch rows i=0..3
        #pragma unroll
        for (int tl = 0; tl < 2; ++tl)
            #pragma unroll
            for (int i = 0; i < 4; ++i)
                hsum_lds[i][ub + tl * 16 + lc] = hsum[tl][i];
    }
    __syncthreads();
    if (w == 0 && l < 40) {
        const int r = l / 10, c = l % 10;
        float acc = 0.f;
        #pragma unroll 8
        for (int u = 0; u < 256; ++u)
            acc += hsum_lds[r][u] * W_fc[u * NCq + c];
        out[(bbase + r) * NCq + c] = acc * (1.0f / Tq) + b_fc[c];
    }
}

extern "C" void kernel_launch(void* const* d_in, const int* in_sizes, int n_in,
                              void* d_out, int out_size, void* d_ws, size_t ws_size,
                              hipStream_t stream) {
    const float* x     = (const float*)d_in[0];
    const float* W_bb  = (const float*)d_in[1];
    const float* b_bb  = (const float*)d_in[2];
    const float* W_ff1 = (const float*)d_in[3];
    const float* b_ff1 = (const float*)d_in[4];
    const float* W_ff2 = (const float*)d_in[5];
    const float* b_ff2 = (const float*)d_in[6];
    const float* W_ta  = (const float*)d_in[7];
    const float* b_ta  = (const float*)d_in[8];
    const float* W_tb  = (const float*)d_in[9];
    const float* b_tb  = (const float*)d_in[10];
    const float* W_fc  = (const float*)d_in[11];
    const float* b_fc  = (const float*)d_in[12];
    float* out = (float*)d_out;

    hipLaunchKernelGGL(cfc_kernel, dim3(256), dim3(512), 0, stream,
                       x, W_bb, b_bb, W_ff1, b_ff1, W_ff2, b_ff2,
                       W_ta, b_ta, W_tb, b_tb, W_fc, b_fc, out);
}

// Round 2
// 2727.283 us; speedup vs baseline: 1.8692x; 1.8692x over previous
//
#include <hip/hip_runtime.h>

#define Tq     2048
#define INq    4
#define UNITSq 256
#define BBq    128
#define NCq    10
#define HBS    288   // hb row stride in elems (256 h + 4 x + 28 zero)

typedef __bf16 bf16x8 __attribute__((ext_vector_type(8)));
typedef float  f32x4  __attribute__((ext_vector_type(4)));
typedef float  f32x2  __attribute__((ext_vector_type(2)));

__device__ __forceinline__ float rcpf(float x) { return __builtin_amdgcn_rcpf(x); }
__device__ __forceinline__ float tanh_f(float x) {          // tanh(x) = 1 - 2/(e^2x+1)
    float e = __expf(x + x);
    return 1.0f - 2.0f * rcpf(e + 1.0f);
}
__device__ __forceinline__ float lecun_f(float x) {         // 1.7159*tanh(0.666x)
    float e = __expf(1.332f * x);
    return 1.7159f - 3.4318f * rcpf(e + 1.0f);
}
__device__ __forceinline__ float sigm_f(float x) {
    return rcpf(1.0f + __expf(-x));
}

// 256 blocks x 512 threads (8 waves). Block owns batch rows [4b,4b+4).
// Wave w: P0 -> 16 backbone cols [16w,16w+16); P1 -> 32 units via u = 32w+2*lc+tl.
__global__ __launch_bounds__(512, 2) void cfc_kernel(
    const float* __restrict__ x,
    const float* __restrict__ W_bb, const float* __restrict__ b_bb,
    const float* __restrict__ W_ff1, const float* __restrict__ b_ff1,
    const float* __restrict__ W_ff2, const float* __restrict__ b_ff2,
    const float* __restrict__ W_ta, const float* __restrict__ b_ta,
    const float* __restrict__ W_tb, const float* __restrict__ b_tb,
    const float* __restrict__ W_fc, const float* __restrict__ b_fc,
    float* __restrict__ out)
{
    const int tid = threadIdx.x;
    const int w   = tid >> 6;
    const int l   = tid & 63;
    const int l4  = l >> 4;      // k-group 0..3
    const int lc  = l & 15;
    const int bbase = blockIdx.x * 4;

    __shared__ __bf16 hb[2][16 * HBS];          // h (cols 0..255) + x-ext (256..259)
    __shared__ __bf16 bbuf[16 * 128];
    __shared__ float  scr[8][384];              // per-wave redistribution scratch
    __shared__ float  xstage[2][512];           // 32 steps x 4 rows x 4
    __shared__ float  hsum_lds[4][256];

    // ---------------- weight preload (B-fragments, register-resident) --------
    // P1 heads: B-frag col lc of tile tl holds unit u = 32w + 2*lc + tl.
    bf16x8 WH[3][2][4];
    #pragma unroll
    for (int tl = 0; tl < 2; ++tl) {
        const int u = w * 32 + 2 * lc + tl;
        #pragma unroll
        for (int kt = 0; kt < 4; ++kt) {
            bf16x8 f1, f2, ts;
            #pragma unroll
            for (int j = 0; j < 8; ++j) {
                const int k = kt * 32 + l4 * 8 + j;
                f1[j] = (__bf16)W_ff1[k * UNITSq + u];
                f2[j] = (__bf16)W_ff2[k * UNITSq + u];
                ts[j] = (__bf16)(W_ta[k * UNITSq + u] + W_tb[k * UNITSq + u]);
            }
            WH[0][tl][kt] = f1; WH[1][tl][kt] = f2; WH[2][tl][kt] = ts;
        }
    }
    // P0 backbone: col = 16w + lc; k enumerates h units 0..255 (kt 0..7), kt 8 = x rows.
    const int cb = w * 16 + lc;
    bf16x8 WB[9];
    #pragma unroll
    for (int kt = 0; kt < 8; ++kt) {
        bf16x8 f;
        #pragma unroll
        for (int j = 0; j < 8; ++j) {
            const int k = kt * 32 + l4 * 8 + j;
            f[j] = (__bf16)W_bb[(4 + k) * BBq + cb];
        }
        WB[kt] = f;
    }
    {
        bf16x8 f;
        #pragma unroll
        for (int j = 0; j < 8; ++j) {
            const int k = l4 * 8 + j;
            f[j] = (k < 4) ? (__bf16)W_bb[k * BBq + cb] : (__bf16)0.0f;
        }
        WB[8] = f;
    }
    // reader-side biases
    const float bias_bb_r = b_bb[w * 16 + lc + 0 * l4] /* col for P0 reader lane l */;
    // NOTE: P0 reader lane l uses col w*16 + (l&15); lc == l&15 so bias_bb_r is correct.
    const int ru0 = w * 32 + 2 * lc;            // P1 reader units (lane l: j=lc)
    const float bf1a = b_ff1[ru0],     bf1b = b_ff1[ru0 + 1];
    const float bf2a = b_ff2[ru0],     bf2b = b_ff2[ru0 + 1];
    const float bta_ = b_ta[ru0] + b_tb[ru0];
    const float btb_ = b_ta[ru0 + 1] + b_tb[ru0 + 1];

    // ---------------- init ---------------------------------------------------
    for (int i = tid; i < 2 * 16 * HBS; i += 512) ((__bf16*)hb)[i] = (__bf16)0.0f;
    for (int i = tid; i < 16 * 128; i += 512) bbuf[i] = (__bf16)0.0f;
    {   // x chunk 0 staged; chunk 1 in flight (reg)
        const int r = tid >> 7, off = tid & 127;
        xstage[0][r * 128 + off] = x[((size_t)(bbase + r) * Tq + (off >> 2)) * INq + (off & 3)];
    }
    float xv;
    {
        const int r = tid >> 7, off = tid & 127;
        xv = x[((size_t)(bbase + r) * Tq + 32 + (off >> 2)) * INq + (off & 3)];
    }
    if (tid < 16) {     // x_0 into hb[0] ext (direct from global; no LDS dep)
        const int r = tid >> 2, q = tid & 3;
        float v = x[((size_t)(bbase + r) * Tq + 0) * INq + q];
        hb[0][(r * HBS + 256 + q) ^ ((r & 7) << 3)] = (__bf16)v;
    }
    __syncthreads();

    float hsumA = 0.f, hsumB = 0.f;
    int cur = 0;
    const int rowc = (lc < 4) ? lc : 3;         // clamped A-row (garbage rows dup row 3)

    for (int t = 0; t < Tq; ++t) {
        const int nxt = cur ^ 1;

        float xnew = 0.f;
        if ((t & 31) == 0) {                    // prefetch chunk (t>>5)+2 into reg
            const int r = tid >> 7, off = tid & 127;
            int tel = t + 64 + (off >> 2);
            tel = (tel < Tq) ? tel : (Tq - 1);
            xnew = x[((size_t)(bbase + r) * Tq + tel) * INq + (off & 3)];
        }

        // ---- P0: pre = [h|x] @ W_bb (K = 288) -------------------------------
        f32x4 a0 = {0.f, 0.f, 0.f, 0.f};
        f32x4 a1 = {0.f, 0.f, 0.f, 0.f};
        #pragma unroll
        for (int kt = 0; kt < 9; ++kt) {
            bf16x8 a = *(const bf16x8*)&hb[cur][(rowc * HBS + kt * 32 + l4 * 8) ^ ((rowc & 7) << 3)];
            if (kt & 1) a1 = __builtin_amdgcn_mfma_f32_16x16x32_bf16(a, WB[kt], a1, 0, 0, 0);
            else        a0 = __builtin_amdgcn_mfma_f32_16x16x32_bf16(a, WB[kt], a0, 0, 0, 0);
        }
        if (l4 == 0) {                          // real rows 0..3 live here
            #pragma unroll
            for (int i = 0; i < 4; ++i) scr[w][i * 16 + lc] = a0[i] + a1[i];
        }
        {   // redistribute: every lane does ONE lecun for (row l>>4, col w*16+(l&15))
            float pre = scr[w][l] + bias_bb_r;
            float v = lecun_f(pre);
            const int r0 = l >> 4;
            bbuf[((r0 * 128) + (w * 16 + lc)) ^ ((r0 & 3) << 5)] = (__bf16)v;
        }
        __syncthreads();    // bar A

        // ---- P1: heads (K = 128) --------------------------------------------
        f32x4 acc[3][2] = {};
        #pragma unroll
        for (int kt = 0; kt < 4; ++kt) {
            bf16x8 a = *(const bf16x8*)&bbuf[(rowc * 128 + kt * 32 + l4 * 8) ^ ((rowc & 3) << 5)];
            #pragma unroll
            for (int hh = 0; hh < 3; ++hh)
                #pragma unroll
                for (int tl = 0; tl < 2; ++tl)
                    acc[hh][tl] = __builtin_amdgcn_mfma_f32_16x16x32_bf16(a, WH[hh][tl][kt], acc[hh][tl], 0, 0, 0);
        }
        if (l4 == 0) {                          // write real pre-acts to wave scratch
            #pragma unroll
            for (int hh = 0; hh < 3; ++hh)
                #pragma unroll
                for (int i = 0; i < 4; ++i)
                    *(f32x2*)&scr[w][hh * 128 + i * 32 + 2 * lc] =
                        (f32x2){acc[hh][0][i], acc[hh][1][i]};
        }
        {   // redistribute: every lane finishes TWO h elems (row l>>4, units ru0,ru0+1)
            const int r0 = l >> 4;
            const int so = r0 * 32 + 2 * lc;
            f32x2 v1 = *(const f32x2*)&scr[w][0 * 128 + so];
            f32x2 v2 = *(const f32x2*)&scr[w][1 * 128 + so];
            f32x2 vt = *(const f32x2*)&scr[w][2 * 128 + so];
            float f1a = tanh_f(v1[0] + bf1a), f1b = tanh_f(v1[1] + bf1b);
            float f2a = tanh_f(v2[0] + bf2a), f2b = tanh_f(v2[1] + bf2b);
            float tta = sigm_f(vt[0] + bta_), ttb = sigm_f(vt[1] + btb_);
            float ha = f1a + tta * (f2a - f1a);
            float hbv = f1b + ttb * (f2b - f1b);
            hsumA += ha; hsumB += hbv;
            union { __bf16 b[2]; unsigned int u; } pk;
            pk.b[0] = (__bf16)ha; pk.b[1] = (__bf16)hbv;
            *(unsigned int*)&hb[nxt][(r0 * HBS + ru0) ^ ((r0 & 7) << 3)] = pk.u;
        }
        if (w == 7 && l < 16 && t + 1 < Tq) {   // x_{t+1} into hb[nxt] ext
            const int r = l >> 2, q = l & 3;
            const int tn = t + 1;
            float v = xstage[(tn >> 5) & 1][r * 128 + (tn & 31) * 4 + q];
            hb[nxt][(r * HBS + 256 + q) ^ ((r & 7) << 3)] = (__bf16)v;
        }
        if ((t & 31) == 0) {                    // stage chunk (t>>5)+1 into LDS
            const int r = tid >> 7, off = tid & 127;
            xstage[((t >> 5) + 1) & 1][r * 128 + off] = xv;
            xv = xnew;
        }
        __syncthreads();    // bar B
        cur = nxt;
    }

    // ---------------- epilogue: out = (hsum/T) @ W_fc + b_fc -----------------
    {
        const int r0 = l >> 4;
        *(f32x2*)&hsum_lds[r0][ru0] = (f32x2){hsumA, hsumB};
    }
    __syncthreads();
    if (w == 0 && l < 40) {
        const int r = l / 10, c = l % 10;
        float s = 0.f;
        #pragma unroll 8
        for (int u = 0; u < 256; ++u)
            s += hsum_lds[r][u] * W_fc[u * NCq + c];
        out[(bbase + r) * NCq + c] = s * (1.0f / Tq) + b_fc[c];
    }
}

extern "C" void kernel_launch(void* const* d_in, const int* in_sizes, int n_in,
                              void* d_out, int out_size, void* d_ws, size_t ws_size,
                              hipStream_t stream) {
    const float* x     = (const float*)d_in[0];
    const float* W_bb  = (const float*)d_in[1];
    const float* b_bb  = (const float*)d_in[2];
    const float* W_ff1 = (const float*)d_in[3];
    const float* b_ff1 = (const float*)d_in[4];
    const float* W_ff2 = (const float*)d_in[5];
    const float* b_ff2 = (const float*)d_in[6];
    const float* W_ta  = (const float*)d_in[7];
    const float* b_ta  = (const float*)d_in[8];
    const float* W_tb  = (const float*)d_in[9];
    const float* b_tb  = (const float*)d_in[10];
    const float* W_fc  = (const float*)d_in[11];
    const float* b_fc  = (const float*)d_in[12];
    float* out = (float*)d_out;

    hipLaunchKernelGGL(cfc_kernel, dim3(256), dim3(512), 0, stream,
                       x, W_bb, b_bb, W_ff1, b_ff1, W_ff2, b_ff2,
                       W_ta, b_ta, W_tb, b_tb, W_fc, b_fc, out);
}

// Round 3
// 1950.324 us; speedup vs baseline: 2.6139x; 1.3984x over previous
//
#include <hip/hip_runtime.h>

#define Tq     2048
#define INq    4
#define UNITSq 256
#define BBq    128
#define NCq    10
#define HBS    288   // hb row stride elems (576B; 576 mod 128 = 64 -> 16-bank parity shift)
#define BBS    160   // bbuf row stride elems (320B; 320 mod 128 = 64)

typedef __bf16 bf16x8 __attribute__((ext_vector_type(8)));
typedef float  f32x4  __attribute__((ext_vector_type(4)));
typedef float  f32x2  __attribute__((ext_vector_type(2)));

__device__ __forceinline__ float rcpf(float x) { return __builtin_amdgcn_rcpf(x); }
__device__ __forceinline__ float tanh_f(float x) {
    float e = __expf(x + x);
    return 1.0f - 2.0f * rcpf(e + 1.0f);
}
__device__ __forceinline__ float lecun_f(float x) {
    float e = __expf(1.332f * x);
    return 1.7159f - 3.4318f * rcpf(e + 1.0f);
}
__device__ __forceinline__ float sigm_f(float x) {
    return rcpf(1.0f + __expf(-x));
}
// select element i (runtime 0..3) from f32x4 via cndmask tree (no scratch)
__device__ __forceinline__ float sel4(f32x4 v, int i) {
    float lo = (i & 1) ? v[1] : v[0];
    float hi = (i & 1) ? v[3] : v[2];
    return (i & 2) ? hi : lo;
}

// 256 blocks x 512 threads (8 waves). Block owns batch rows [4b,4b+4).
// 4x ROW REPLICATION: A-tile row j holds real row (j&3)  ->  C/D reg i holds
// real row i in EVERY lane -> post-MFMA redistribution is a register select.
__global__ __launch_bounds__(512, 2) void cfc_kernel(
    const float* __restrict__ x,
    const float* __restrict__ W_bb, const float* __restrict__ b_bb,
    const float* __restrict__ W_ff1, const float* __restrict__ b_ff1,
    const float* __restrict__ W_ff2, const float* __restrict__ b_ff2,
    const float* __restrict__ W_ta, const float* __restrict__ b_ta,
    const float* __restrict__ W_tb, const float* __restrict__ b_tb,
    const float* __restrict__ W_fc, const float* __restrict__ b_fc,
    float* __restrict__ out)
{
    const int tid = threadIdx.x;
    const int w   = tid >> 6;
    const int l   = tid & 63;
    const int l4  = l >> 4;      // k-group / row-select
    const int lc  = l & 15;
    const int bbase = blockIdx.x * 4;

    __shared__ __bf16 hb[4 * HBS];       // single buffer: cols 0..255 h, 256..259 x, rest 0
    __shared__ __bf16 bbuf[4 * BBS];     // cols 0..127 backbone acts
    __shared__ float  xstage[2][512];    // 32 steps x 4 rows x 4
    __shared__ float  hsum_lds[4][256];

    // ---------------- weight preload (register-resident B-fragments) ---------
    // P1 heads: tile tl col lc -> unit u = 32w + 2*lc + tl
    bf16x8 WH[3][2][4];
    #pragma unroll
    for (int tl = 0; tl < 2; ++tl) {
        const int u = w * 32 + 2 * lc + tl;
        #pragma unroll
        for (int kt = 0; kt < 4; ++kt) {
            bf16x8 f1, f2, ts;
            #pragma unroll
            for (int j = 0; j < 8; ++j) {
                const int k = kt * 32 + l4 * 8 + j;
                f1[j] = (__bf16)W_ff1[k * UNITSq + u];
                f2[j] = (__bf16)W_ff2[k * UNITSq + u];
                ts[j] = (__bf16)(W_ta[k * UNITSq + u] + W_tb[k * UNITSq + u]);
            }
            WH[0][tl][kt] = f1; WH[1][tl][kt] = f2; WH[2][tl][kt] = ts;
        }
    }
    // P0 backbone: col cb = 16w + lc; kt 0..7 = h rows 4..259, kt 8 = x rows 0..3
    const int cb = w * 16 + lc;
    bf16x8 WB[9];
    #pragma unroll
    for (int kt = 0; kt < 8; ++kt) {
        bf16x8 f;
        #pragma unroll
        for (int j = 0; j < 8; ++j) {
            const int k = kt * 32 + l4 * 8 + j;
            f[j] = (__bf16)W_bb[(4 + k) * BBq + cb];
        }
        WB[kt] = f;
    }
    {
        bf16x8 f;
        #pragma unroll
        for (int j = 0; j < 8; ++j) {
            const int k = l4 * 8 + j;
            f[j] = (k < 4) ? (__bf16)W_bb[k * BBq + cb] : (__bf16)0.0f;
        }
        WB[8] = f;
    }
    const float bias_bb_r = b_bb[cb];
    const int ru0 = w * 32 + 2 * lc;
    const float bf1a = b_ff1[ru0], bf1b = b_ff1[ru0 + 1];
    const float bf2a = b_ff2[ru0], bf2b = b_ff2[ru0 + 1];
    const float bta_ = b_ta[ru0] + b_tb[ru0];
    const float btb_ = b_ta[ru0 + 1] + b_tb[ru0 + 1];

    // ---------------- init ---------------------------------------------------
    for (int i = tid; i < 4 * HBS; i += 512) hb[i] = (__bf16)0.0f;
    {
        const int r = tid >> 7, off = tid & 127;
        xstage[0][r * 128 + off] = x[((size_t)(bbase + r) * Tq + (off >> 2)) * INq + (off & 3)];
    }
    float xv;
    {
        const int r = tid >> 7, off = tid & 127;
        xv = x[((size_t)(bbase + r) * Tq + 32 + (off >> 2)) * INq + (off & 3)];
    }
    if (tid < 16) {
        const int r = tid >> 2, q = tid & 3;
        hb[r * HBS + 256 + q] = (__bf16)x[((size_t)(bbase + r) * Tq + 0) * INq + q];
    }
    __syncthreads();

    float hsumA = 0.f, hsumB = 0.f;
    const int rowc = lc & 3;             // replicated A-row

    for (int t = 0; t < Tq; ++t) {
        float xnew = 0.f;
        if ((t & 31) == 0) {             // prefetch chunk (t>>5)+2 into reg
            const int r = tid >> 7, off = tid & 127;
            int tel = t + 64 + (off >> 2);
            tel = (tel < Tq) ? tel : (Tq - 1);
            xnew = x[((size_t)(bbase + r) * Tq + tel) * INq + (off & 3)];
        }

        // ---- P0: pre = [h|x] @ W_bb (K = 288), 4-way acc split --------------
        f32x4 p0 = {0.f,0.f,0.f,0.f}, p1 = {0.f,0.f,0.f,0.f};
        f32x4 p2 = {0.f,0.f,0.f,0.f}, p3 = {0.f,0.f,0.f,0.f};
        #pragma unroll
        for (int kt = 0; kt < 9; ++kt) {
            bf16x8 a = *(const bf16x8*)&hb[rowc * HBS + kt * 32 + l4 * 8];
            switch (kt & 3) {
                case 0: p0 = __builtin_amdgcn_mfma_f32_16x16x32_bf16(a, WB[kt], p0, 0, 0, 0); break;
                case 1: p1 = __builtin_amdgcn_mfma_f32_16x16x32_bf16(a, WB[kt], p1, 0, 0, 0); break;
                case 2: p2 = __builtin_amdgcn_mfma_f32_16x16x32_bf16(a, WB[kt], p2, 0, 0, 0); break;
                case 3: p3 = __builtin_amdgcn_mfma_f32_16x16x32_bf16(a, WB[kt], p3, 0, 0, 0); break;
            }
        }
        {
            f32x4 s = (p0 + p1) + (p2 + p3);
            float pre = sel4(s, l4) + bias_bb_r;     // this lane: row l4, col cb
            bbuf[l4 * BBS + cb] = (__bf16)lecun_f(pre);
        }
        __syncthreads();    // bar A

        // ---- P1: heads (K = 128) --------------------------------------------
        f32x4 acc[3][2] = {};
        #pragma unroll
        for (int kt = 0; kt < 4; ++kt) {
            bf16x8 a = *(const bf16x8*)&bbuf[rowc * BBS + kt * 32 + l4 * 8];
            #pragma unroll
            for (int hh = 0; hh < 3; ++hh)
                #pragma unroll
                for (int tl = 0; tl < 2; ++tl)
                    acc[hh][tl] = __builtin_amdgcn_mfma_f32_16x16x32_bf16(a, WH[hh][tl][kt], acc[hh][tl], 0, 0, 0);
        }
        {   // this lane: row l4, units ru0, ru0+1 (register selects, no LDS)
            float f1a = tanh_f(sel4(acc[0][0], l4) + bf1a);
            float f1b = tanh_f(sel4(acc[0][1], l4) + bf1b);
            float f2a = tanh_f(sel4(acc[1][0], l4) + bf2a);
            float f2b = tanh_f(sel4(acc[1][1], l4) + bf2b);
            float tta = sigm_f(sel4(acc[2][0], l4) + bta_);
            float ttb = sigm_f(sel4(acc[2][1], l4) + btb_);
            float ha  = f1a + tta * (f2a - f1a);
            float hbv = f1b + ttb * (f2b - f1b);
            hsumA += ha; hsumB += hbv;
            union { __bf16 b[2]; unsigned int u; } pk;
            pk.b[0] = (__bf16)ha; pk.b[1] = (__bf16)hbv;
            *(unsigned int*)&hb[l4 * HBS + ru0] = pk.u;
        }
        if (w == 7 && l < 16 && t + 1 < Tq) {   // x_{t+1} into hb ext cols
            const int r = l >> 2, q = l & 3;
            const int tn = t + 1;
            hb[r * HBS + 256 + q] = (__bf16)xstage[(tn >> 5) & 1][r * 128 + (tn & 31) * 4 + q];
        }
        if ((t & 31) == 0) {
            const int r = tid >> 7, off = tid & 127;
            xstage[((t >> 5) + 1) & 1][r * 128 + off] = xv;
            xv = xnew;
        }
        __syncthreads();    // bar B
    }

    // ---------------- epilogue: out = (hsum/T) @ W_fc + b_fc -----------------
    *(f32x2*)&hsum_lds[l4][ru0] = (f32x2){hsumA, hsumB};
    __syncthreads();
    if (w == 0 && l < 40) {
        const int r = l / 10, c = l % 10;
        float s = 0.f;
        #pragma unroll 8
        for (int u = 0; u < 256; ++u)
            s += hsum_lds[r][u] * W_fc[u * NCq + c];
        out[(bbase + r) * NCq + c] = s * (1.0f / Tq) + b_fc[c];
    }
}

extern "C" void kernel_launch(void* const* d_in, const int* in_sizes, int n_in,
                              void* d_out, int out_size, void* d_ws, size_t ws_size,
                              hipStream_t stream) {
    const float* x     = (const float*)d_in[0];
    const float* W_bb  = (const float*)d_in[1];
    const float* b_bb  = (const float*)d_in[2];
    const float* W_ff1 = (const float*)d_in[3];
    const float* b_ff1 = (const float*)d_in[4];
    const float* W_ff2 = (const float*)d_in[5];
    const float* b_ff2 = (const float*)d_in[6];
    const float* W_ta  = (const float*)d_in[7];
    const float* b_ta  = (const float*)d_in[8];
    const float* W_tb  = (const float*)d_in[9];
    const float* b_tb  = (const float*)d_in[10];
    const float* W_fc  = (const float*)d_in[11];
    const float* b_fc  = (const float*)d_in[12];
    float* out = (float*)d_out;

    hipLaunchKernelGGL(cfc_kernel, dim3(256), dim3(512), 0, stream,
                       x, W_bb, b_bb, W_ff1, b_ff1, W_ff2, b_ff2,
                       W_ta, b_ta, W_tb, b_tb, W_fc, b_fc, out);
}